// Round 13
// baseline (69.471 us; speedup 1.0000x reference)
//
#include <hip/hip_runtime.h>
#include <hip/hip_bf16.h>

#define TT 2048
#define BATCH 8
#define MROWS (BATCH*TT)   // 16384
#define AW 8               // waves per attn block

typedef __attribute__((ext_vector_type(8))) short bf16x8;   // MFMA A/B frag (4 VGPR)
typedef __attribute__((ext_vector_type(4))) short s16x4;
typedef __attribute__((ext_vector_type(4))) float f32x4;    // MFMA C/D frag

__device__ __forceinline__ short f2bf(float f) {
    union { __hip_bfloat16 h; short s; } u;
    u.h = __float2bfloat16(f);
    return u.s;
}
__device__ __forceinline__ float bf2f(short s) {
    union { unsigned u; float f; } u;
    u.u = ((unsigned)(unsigned short)s) << 16;
    return u.f;
}

typedef __attribute__((address_space(3))) unsigned int       lds_u32_t;
typedef const __attribute__((address_space(1))) unsigned int g_u32_t;
__device__ __forceinline__ void gl_lds16(const void* g, void* l) {
    __builtin_amdgcn_global_load_lds((g_u32_t*)g, (lds_u32_t*)l, 16, 0, 0);
}

// ---------------------------------------------------------------------------
// W transpose: Wq|Wk|Wv [1024][64] f32 -> wt [192][1024] bf16 (row n = col of W)
// Wq gets scale = (1/32)*log2(e) folded in (softmax scale + exp->exp2).
// ---------------------------------------------------------------------------
__global__ __launch_bounds__(256) void wtrans_kernel(
    const float* __restrict__ Wk, const float* __restrict__ Wq,
    const float* __restrict__ Wv, short* __restrict__ wt)
{
    __shared__ float tile[64][68];
    const int mat = blockIdx.x >> 4;           // 0=q,1=k,2=v
    const int k0  = (blockIdx.x & 15) * 64;
    const float* W = (mat == 0) ? Wq : (mat == 1) ? Wk : Wv;
    const float scl = (mat == 0) ? 0.04508422002778011f : 1.0f;  // (1/32)*log2(e)
    const int t = threadIdx.x;
    const int row = t >> 2, quad = t & 3;
    #pragma unroll
    for (int i = 0; i < 4; i++) {
        float4 v = *(const float4*)(W + (size_t)(k0 + row) * 64 + quad * 16 + i * 4);
        *(float4*)&tile[row][quad * 16 + i * 4] = v;
    }
    __syncthreads();
    short tmp[16];
    #pragma unroll
    for (int j = 0; j < 16; j++) tmp[j] = f2bf(tile[quad * 16 + j][row] * scl);
    short* dst = wt + (size_t)(mat * 64 + row) * 1024 + k0 + quad * 16;
    #pragma unroll
    for (int j2 = 0; j2 < 2; j2++) {
        bf16x8 o;
        #pragma unroll
        for (int jj = 0; jj < 8; jj++) o[jj] = tmp[j2 * 8 + jj];
        *(bf16x8*)(dst + j2 * 8) = o;
    }
}

// ---------------------------------------------------------------------------
// Projection v8: BM=32, BN=96 (N-split), BK=128, 256 thr, grid=1024 (2/CU).
// 8 barrier steps (vs R8's 16) at 2 blocks/CU (vs R11's 1): exposure ~halved.
// A staged bf16 via registers (swizzled ds_write_b128); B via global_load_lds
// with pre-swizzled source. nh=0 blocks: q + k[0:32]; nh=1: k[32:64] + V^T.
// ---------------------------------------------------------------------------
__global__ __launch_bounds__(256, 2) void proj_kernel(
    const float* __restrict__ x, const short* __restrict__ wt,
    short* __restrict__ qb, short* __restrict__ kb, short* __restrict__ vtb)
{
    // [0,16384): As [2][32][128] bf16 (8192 B/buf)
    // [16384,65536): Bs [2][96][128] bf16 (24576 B/buf)
    __shared__ __align__(16) char lds[65536];

    const int tid  = threadIdx.x;
    const int lane = tid & 63, w = tid >> 6;
    const int l15  = lane & 15, g = lane >> 4;
    const int x7   = l15 & 7;
    const int wr   = w & 1;              // rows wr*16..+15
    const int wc   = w >> 1;             // cols wc*48..+47 (within the 96)
    const int nh   = blockIdx.x & 1;     // N half: cols nh*96..+95 globally
    const int r0   = (blockIdx.x >> 1) * 32;

    // ---- A staging (register path): thread owns (row=tid>>3, 16-f32 seg)
    const int arow_s = tid >> 3, aseg = tid & 7;
    const float* xsrc = x + (size_t)(r0 + arow_s) * 1024 + aseg * 16;
    const int ac0 = ((aseg * 2)     ^ (arow_s & 7)) * 16;   // byte off in 256B row
    const int ac1 = ((aseg * 2 + 1) ^ (arow_s & 7)) * 16;

    // ---- B staging (gl_lds): wave issues j=0..5; jp covers 4 rows (1024 B)
    const short* bg[6]; unsigned bOff[6];
    #pragma unroll
    for (int j = 0; j < 6; j++) {
        const int jp   = w * 6 + j;                 // 0..23
        const int row  = jp * 4 + (lane >> 4);      // 0..95
        const int slot = (lane & 15) ^ (row & 7);   // pre-swizzled source unit
        bg[j]   = wt + (size_t)(nh * 96 + row) * 1024 + slot * 8;
        bOff[j] = jp * 1024;                        // wave-uniform LDS base
    }

    f32x4 acc[3];
    #pragma unroll
    for (int nt = 0; nt < 3; nt++) acc[nt] = (f32x4){0.f, 0.f, 0.f, 0.f};

    // ---- prologue: stage k-tile 0 into buffer 0
    {
        float4 a0 = *(const float4*)(xsrc);
        float4 a1 = *(const float4*)(xsrc + 4);
        float4 a2 = *(const float4*)(xsrc + 8);
        float4 a3 = *(const float4*)(xsrc + 12);
        #pragma unroll
        for (int j = 0; j < 6; j++) gl_lds16(bg[j], lds + 16384 + bOff[j]);
        bf16x8 c0 = { f2bf(a0.x), f2bf(a0.y), f2bf(a0.z), f2bf(a0.w),
                      f2bf(a1.x), f2bf(a1.y), f2bf(a1.z), f2bf(a1.w) };
        bf16x8 c1 = { f2bf(a2.x), f2bf(a2.y), f2bf(a2.z), f2bf(a2.w),
                      f2bf(a3.x), f2bf(a3.y), f2bf(a3.z), f2bf(a3.w) };
        *(bf16x8*)(lds + arow_s * 256 + ac0) = c0;
        *(bf16x8*)(lds + arow_s * 256 + ac1) = c1;
    }
    __syncthreads();

    #pragma unroll
    for (int ks = 0; ks < 8; ks++) {
        const int cur = ks & 1;
        const int nb  = cur ^ 1;

        // issue next tile's loads first (latency hides under this step)
        float4 a0, a1, a2, a3;
        if (ks < 7) {
            a0 = *(const float4*)(xsrc + (ks + 1) * 128);
            a1 = *(const float4*)(xsrc + (ks + 1) * 128 + 4);
            a2 = *(const float4*)(xsrc + (ks + 1) * 128 + 8);
            a3 = *(const float4*)(xsrc + (ks + 1) * 128 + 12);
            #pragma unroll
            for (int j = 0; j < 6; j++)
                gl_lds16(bg[j] + (ks + 1) * 128, lds + 16384 + nb * 24576 + bOff[j]);
        }

        const char*  Ab = lds + cur * 8192;
        const short* Bb = (const short*)(lds + 16384 + cur * 24576);

        // frags (reads swizzle-consistent with writes: row&7 == l15&7 == x7)
        bf16x8 af[4];
        {
            const int arow = wr * 16 + l15;
            #pragma unroll
            for (int kc = 0; kc < 4; kc++)
                af[kc] = *(const bf16x8*)(Ab + arow * 256 + (((kc * 4 + g) ^ x7) * 16));
        }
        bf16x8 bfr[3][4];
        #pragma unroll
        for (int nt = 0; nt < 3; nt++)
            #pragma unroll
            for (int kc = 0; kc < 4; kc++)
                bfr[nt][kc] = *(const bf16x8*)(
                    Bb + (wc * 48 + nt * 16 + l15) * 128 + (((kc * 4 + g) ^ x7) * 8));

        #pragma unroll
        for (int kc = 0; kc < 4; kc++)
            #pragma unroll
            for (int nt = 0; nt < 3; nt++)
                acc[nt] = __builtin_amdgcn_mfma_f32_16x16x32_bf16(
                    af[kc], bfr[nt][kc], acc[nt], 0, 0, 0);

        // write next A tile (loads have had the whole compute to land)
        if (ks < 7) {
            bf16x8 c0 = { f2bf(a0.x), f2bf(a0.y), f2bf(a0.z), f2bf(a0.w),
                          f2bf(a1.x), f2bf(a1.y), f2bf(a1.z), f2bf(a1.w) };
            bf16x8 c1 = { f2bf(a2.x), f2bf(a2.y), f2bf(a2.z), f2bf(a2.w),
                          f2bf(a3.x), f2bf(a3.y), f2bf(a3.z), f2bf(a3.w) };
            *(bf16x8*)(lds + nb * 8192 + arow_s * 256 + ac0) = c0;
            *(bf16x8*)(lds + nb * 8192 + arow_s * 256 + ac1) = c1;
        }
        __syncthreads();
    }

    // ---- epilogue: q,k direct; v via LDS transpose (nh=1 blocks only)
    const int bi  = r0 >> 11;
    const int sl0 = r0 & 2047;
    short* vsl = (short*)lds;            // [32][66] overlay on As region
    #pragma unroll
    for (int nt = 0; nt < 3; nt++) {
        const int c = nh * 96 + wc * 48 + nt * 16 + l15;   // global col 0..191
        #pragma unroll
        for (int r = 0; r < 4; r++) {
            const int lrow = wr * 16 + g * 4 + r;
            const int row  = r0 + lrow;
            const short v = f2bf(acc[nt][r]);
            if (c < 64)        qb[(size_t)row * 64 + c] = v;
            else if (c < 128)  kb[(size_t)row * 64 + (c - 64)] = v;
            else               vsl[lrow * 66 + (c - 128)] = v;
        }
    }
    __syncthreads();
    if (nh == 1) {   // vt[b][col][seq]: thread owns (col, 8-seq segment)
        const int col = tid >> 2, seg = tid & 3;
        short tmp[8];
        #pragma unroll
        for (int j = 0; j < 8; j++) tmp[j] = vsl[(seg * 8 + j) * 66 + col];
        bf16x8 o;
        #pragma unroll
        for (int jj = 0; jj < 8; jj++) o[jj] = tmp[jj];
        *(bf16x8*)(vtb + ((size_t)bi * 64 + col) * TT + sl0 + seg * 8) = o;
    }
}

// ---------------------------------------------------------------------------
// Flash attention v5 (reverted to measured-best): swapped QK^T + in-register
// softmax, split-kv over 8 waves with LDS merge, software-pipelined K/V loads.
// ---------------------------------------------------------------------------
__global__ __launch_bounds__(512, 2)
void attn_kernel(
    const short* __restrict__ qb, const short* __restrict__ kb,
    const short* __restrict__ vtb, float* __restrict__ out)
{
    __shared__ __align__(16) char smem[AW * 4608];
    __shared__ float ml[AW][64];   // [w][0..31]=m, [w][32..63]=l

    const int tid  = threadIdx.x;
    const int w    = tid >> 6, lane = tid & 63;
    const int l15  = lane & 15, g = lane >> 4;
    const int b    = blockIdx.x & 7;
    const int qt   = 63 - (blockIdx.x >> 3);
    const int r0   = qt * 32;
    const int nkv  = (r0 >> 6) + 1;

    short* ps = (short*)(smem + w * 4608);   // [32][72]

    const short* q  = qb  + (size_t)b * TT * 64;
    const short* k  = kb  + (size_t)b * TT * 64;
    const short* vt = vtb + (size_t)b * 64 * TT;

    bf16x8 qf[2][2];
    #pragma unroll
    for (int rt = 0; rt < 2; rt++)
        #pragma unroll
        for (int kc = 0; kc < 2; kc++)
            qf[rt][kc] = *(const bf16x8*)(q + (size_t)(r0 + rt * 16 + l15) * 64 + kc * 32 + g * 8);

    f32x4 o[2][4];
    float m_[2] = { -INFINITY, -INFINITY };
    float l_[2] = { 0.f, 0.f };
    #pragma unroll
    for (int rt = 0; rt < 2; rt++)
        #pragma unroll
        for (int ht = 0; ht < 4; ht++) o[rt][ht] = (f32x4){0.f, 0.f, 0.f, 0.f};

    bf16x8 kf[4][2];
    if (w < nkv) {
        #pragma unroll
        for (int nt = 0; nt < 4; nt++)
            #pragma unroll
            for (int kc = 0; kc < 2; kc++)
                kf[nt][kc] = *(const bf16x8*)(
                    k + (size_t)(w * 64 + nt * 16 + l15) * 64 + kc * 32 + g * 8);
    }

    for (int t = w; t < nkv; t += AW) {
        const int s0 = t * 64;
        const bool diag = (t == nkv - 1);
        const bool more = (t + AW < nkv);

        f32x4 s[2][4];
        #pragma unroll
        for (int rt = 0; rt < 2; rt++)
            #pragma unroll
            for (int nt = 0; nt < 4; nt++) s[rt][nt] = (f32x4){0.f, 0.f, 0.f, 0.f};
        #pragma unroll
        for (int kc = 0; kc < 2; kc++)
            #pragma unroll
            for (int rt = 0; rt < 2; rt++)
                #pragma unroll
                for (int nt = 0; nt < 4; nt++)
                    s[rt][nt] = __builtin_amdgcn_mfma_f32_16x16x32_bf16(
                        kf[nt][kc], qf[rt][kc], s[rt][nt], 0, 0, 0);

        bf16x8 vf[4][2];
        #pragma unroll
        for (int ht = 0; ht < 4; ht++)
            #pragma unroll
            for (int kc = 0; kc < 2; kc++)
                vf[ht][kc] = *(const bf16x8*)(
                    vt + (size_t)(ht * 16 + l15) * TT + s0 + kc * 32 + g * 8);
        bf16x8 kfn[4][2];
        if (more) {
            #pragma unroll
            for (int nt = 0; nt < 4; nt++)
                #pragma unroll
                for (int kc = 0; kc < 2; kc++)
                    kfn[nt][kc] = *(const bf16x8*)(
                        k + (size_t)(s0 + AW * 64 + nt * 16 + l15) * 64 + kc * 32 + g * 8);
        }

        if (diag) {
            #pragma unroll
            for (int rt = 0; rt < 2; rt++) {
                const int qg = r0 + rt * 16 + l15;
                #pragma unroll
                for (int nt = 0; nt < 4; nt++)
                    #pragma unroll
                    for (int r = 0; r < 4; r++)
                        if (s0 + nt * 16 + g * 4 + r > qg) s[rt][nt][r] = -INFINITY;
            }
        }

        #pragma unroll
        for (int rt = 0; rt < 2; rt++) {
            float a0 = fmaxf(fmaxf(s[rt][0][0], s[rt][0][1]), fmaxf(s[rt][0][2], s[rt][0][3]));
            float a1 = fmaxf(fmaxf(s[rt][1][0], s[rt][1][1]), fmaxf(s[rt][1][2], s[rt][1][3]));
            float a2 = fmaxf(fmaxf(s[rt][2][0], s[rt][2][1]), fmaxf(s[rt][2][2], s[rt][2][3]));
            float a3 = fmaxf(fmaxf(s[rt][3][0], s[rt][3][1]), fmaxf(s[rt][3][2], s[rt][3][3]));
            float tm = fmaxf(fmaxf(a0, a1), fmaxf(a2, a3));
            tm = fmaxf(tm, __shfl_xor(tm, 16));
            tm = fmaxf(tm, __shfl_xor(tm, 32));

            const float mn = fmaxf(m_[rt], tm);
            const float al = __builtin_amdgcn_exp2f(m_[rt] - mn);
            m_[rt] = mn;

            #pragma unroll
            for (int nt = 0; nt < 4; nt++)
                #pragma unroll
                for (int r = 0; r < 4; r++)
                    s[rt][nt][r] = __builtin_amdgcn_exp2f(s[rt][nt][r] - mn);

            float b0 = (s[rt][0][0] + s[rt][0][1]) + (s[rt][0][2] + s[rt][0][3]);
            float b1 = (s[rt][1][0] + s[rt][1][1]) + (s[rt][1][2] + s[rt][1][3]);
            float b2 = (s[rt][2][0] + s[rt][2][1]) + (s[rt][2][2] + s[rt][2][3]);
            float b3 = (s[rt][3][0] + s[rt][3][1]) + (s[rt][3][2] + s[rt][3][3]);
            float ts = (b0 + b1) + (b2 + b3);
            ts += __shfl_xor(ts, 16);
            ts += __shfl_xor(ts, 32);
            l_[rt] = l_[rt] * al + ts;

            float ab[4];
            #pragma unroll
            for (int r = 0; r < 4; r++) ab[r] = __shfl(al, g * 4 + r);
            #pragma unroll
            for (int ht = 0; ht < 4; ht++)
                #pragma unroll
                for (int r = 0; r < 4; r++)
                    o[rt][ht][r] *= ab[r];

            #pragma unroll
            for (int nt = 0; nt < 4; nt++) {
                s16x4 pk = { f2bf(s[rt][nt][0]), f2bf(s[rt][nt][1]),
                             f2bf(s[rt][nt][2]), f2bf(s[rt][nt][3]) };
                *(s16x4*)&ps[(rt * 16 + l15) * 72 + nt * 16 + g * 4] = pk;
            }
        }

        bf16x8 pf[2][2];
        #pragma unroll
        for (int rt = 0; rt < 2; rt++)
            #pragma unroll
            for (int kc = 0; kc < 2; kc++)
                pf[rt][kc] = *(const bf16x8*)&ps[(rt * 16 + l15) * 72 + kc * 32 + g * 8];
        #pragma unroll
        for (int kc = 0; kc < 2; kc++)
            #pragma unroll
            for (int rt = 0; rt < 2; rt++)
                #pragma unroll
                for (int ht = 0; ht < 4; ht++)
                    o[rt][ht] = __builtin_amdgcn_mfma_f32_16x16x32_bf16(
                        pf[rt][kc], vf[ht][kc], o[rt][ht], 0, 0, 0);

        if (more) {
            #pragma unroll
            for (int nt = 0; nt < 4; nt++)
                #pragma unroll
                for (int kc = 0; kc < 2; kc++)
                    kf[nt][kc] = kfn[nt][kc];
        }
    }

    if (g == 0) {
        #pragma unroll
        for (int rt = 0; rt < 2; rt++) {
            ml[w][rt * 16 + l15]      = m_[rt];
            ml[w][32 + rt * 16 + l15] = l_[rt];
        }
    }
    short* pO = ps;   // [32][68] bf16 (ps is dead now)
    #pragma unroll
    for (int rt = 0; rt < 2; rt++)
        #pragma unroll
        for (int ht = 0; ht < 4; ht++)
            #pragma unroll
            for (int r = 0; r < 4; r++)
                pO[(rt * 16 + g * 4 + r) * 68 + ht * 16 + l15] = f2bf(o[rt][ht][r]);
    __syncthreads();

    {
        const int row = tid >> 4, seg = tid & 15;
        float gm = -INFINITY;
        #pragma unroll
        for (int w2 = 0; w2 < AW; w2++) gm = fmaxf(gm, ml[w2][row]);
        float accL = 0.f;
        float accO[4] = {0.f, 0.f, 0.f, 0.f};
        #pragma unroll
        for (int w2 = 0; w2 < AW; w2++) {
            const float sc = __builtin_amdgcn_exp2f(ml[w2][row] - gm);
            accL = fmaf(sc, ml[w2][32 + row], accL);
            const s16x4 ov = *(const s16x4*)((const short*)(smem + w2 * 4608) + row * 68 + seg * 4);
            #pragma unroll
            for (int j = 0; j < 4; j++)
                accO[j] = fmaf(sc, bf2f(ov[j]), accO[j]);
        }
        const float inv = 1.f / accL;
        float4 res = make_float4(accO[0] * inv, accO[1] * inv, accO[2] * inv, accO[3] * inv);
        *(float4*)(out + ((size_t)b * TT + r0 + row) * 64 + seg * 4) = res;
    }
}

extern "C" void kernel_launch(void* const* d_in, const int* in_sizes, int n_in,
                              void* d_out, int out_size, void* d_ws, size_t ws_size,
                              hipStream_t stream) {
    const float* x  = (const float*)d_in[0];
    const float* Wk = (const float*)d_in[1];
    const float* Wq = (const float*)d_in[2];
    const float* Wv = (const float*)d_in[3];
    float* outp = (float*)d_out;

    short* wt  = (short*)d_ws;                     // [192][1024] bf16
    short* qb  = wt + (size_t)192 * 1024;          // [16384][64] bf16 (pre-scaled)
    short* kb  = qb + (size_t)MROWS * 64;          // [16384][64] bf16
    short* vtb = kb + (size_t)MROWS * 64;          // [8][64][2048] bf16 (V^T)

    wtrans_kernel<<<48, 256, 0, stream>>>(Wk, Wq, Wv, wt);
    proj_kernel<<<(MROWS / 32) * 2, 256, 0, stream>>>(x, wt, qb, kb, vtb);
    attn_kernel<<<BATCH * 64, 512, 0, stream>>>(qb, kb, vtb, outp);
}

// Round 14
// 53.077 us; speedup vs baseline: 1.3089x; 1.3089x over previous
//
#include <hip/hip_runtime.h>
#include <hip/hip_bf16.h>

#define TT 2048
#define BATCH 8
#define MROWS (BATCH*TT)   // 16384
#define AW 8               // waves per attn block

typedef __attribute__((ext_vector_type(8))) short bf16x8;   // MFMA A/B frag (4 VGPR)
typedef __attribute__((ext_vector_type(4))) short s16x4;
typedef __attribute__((ext_vector_type(4))) float f32x4;    // MFMA C/D frag

__device__ __forceinline__ short f2bf(float f) {
    union { __hip_bfloat16 h; short s; } u;
    u.h = __float2bfloat16(f);
    return u.s;
}
__device__ __forceinline__ float bf2f(short s) {
    union { unsigned u; float f; } u;
    u.u = ((unsigned)(unsigned short)s) << 16;
    return u.f;
}

// ---------------------------------------------------------------------------
// W transpose: Wq|Wk|Wv [1024][64] f32 -> wt [192][1024] bf16 (row n = col of W)
// Wq gets scale = (1/32)*log2(e) folded in (softmax scale + exp->exp2).
// ---------------------------------------------------------------------------
__global__ __launch_bounds__(256) void wtrans_kernel(
    const float* __restrict__ Wk, const float* __restrict__ Wq,
    const float* __restrict__ Wv, short* __restrict__ wt)
{
    __shared__ float tile[64][68];
    const int mat = blockIdx.x >> 4;           // 0=q,1=k,2=v
    const int k0  = (blockIdx.x & 15) * 64;
    const float* W = (mat == 0) ? Wq : (mat == 1) ? Wk : Wv;
    const float scl = (mat == 0) ? 0.04508422002778011f : 1.0f;  // (1/32)*log2(e)
    const int t = threadIdx.x;
    const int row = t >> 2, quad = t & 3;
    #pragma unroll
    for (int i = 0; i < 4; i++) {
        float4 v = *(const float4*)(W + (size_t)(k0 + row) * 64 + quad * 16 + i * 4);
        *(float4*)&tile[row][quad * 16 + i * 4] = v;
    }
    __syncthreads();
    short tmp[16];
    #pragma unroll
    for (int j = 0; j < 16; j++) tmp[j] = f2bf(tile[quad * 16 + j][row] * scl);
    short* dst = wt + (size_t)(mat * 64 + row) * 1024 + k0 + quad * 16;
    #pragma unroll
    for (int j2 = 0; j2 < 2; j2++) {
        bf16x8 o;
        #pragma unroll
        for (int jj = 0; jj < 8; jj++) o[jj] = tmp[j2 * 8 + jj];
        *(bf16x8*)(dst + j2 * 8) = o;
    }
}

// ---------------------------------------------------------------------------
// Projection (RESTORED R2/R3 kernel — measured ~18-19 µs by subtraction,
// best of all 6 proj variants tried): BM=64, 256 thr (4 waves), 16 k-steps.
// x staged to LDS bf16 via registers (double-buffered, 1 barrier/step);
// B frags DIRECT from L2-resident wt. Wave w owns cols [w*48, w*48+48).
// ---------------------------------------------------------------------------
__global__ __launch_bounds__(256) void proj_kernel(
    const float* __restrict__ x, const short* __restrict__ wt,
    short* __restrict__ qb, short* __restrict__ kb, short* __restrict__ vtb)
{
    __shared__ short xs[2][64][72];
    __shared__ short vsl[64][66];
    const int tid  = threadIdx.x;
    const int lane = tid & 63, w = tid >> 6;
    const int l15  = lane & 15, g = lane >> 4;
    const int r0   = blockIdx.x * 64;
    const int xrow = tid >> 2, xquad = tid & 3;

    f32x4 acc[4][3];
    #pragma unroll
    for (int rt = 0; rt < 4; rt++)
        #pragma unroll
        for (int nt = 0; nt < 3; nt++)
            acc[rt][nt] = (f32x4){0.f, 0.f, 0.f, 0.f};

    const float* xbase = x + (size_t)(r0 + xrow) * 1024 + xquad * 16;

    float4 xr[4];
    #pragma unroll
    for (int i = 0; i < 4; i++) xr[i] = *(const float4*)(xbase + i * 4);
    #pragma unroll
    for (int i = 0; i < 4; i++) {
        s16x4 s = { f2bf(xr[i].x), f2bf(xr[i].y), f2bf(xr[i].z), f2bf(xr[i].w) };
        *(s16x4*)&xs[0][xrow][xquad * 16 + i * 4] = s;
    }

    int cur = 0;
    for (int ks = 0; ks < 16; ks++) {
        const int k0 = ks * 64;
        if (ks < 15) {   // issue next x tile loads early (hide under MFMA)
            #pragma unroll
            for (int i = 0; i < 4; i++) xr[i] = *(const float4*)(xbase + k0 + 64 + i * 4);
        }
        bf16x8 bfrag[3][2];
        #pragma unroll
        for (int nt = 0; nt < 3; nt++)
            #pragma unroll
            for (int kc = 0; kc < 2; kc++)
                bfrag[nt][kc] = *(const bf16x8*)(
                    wt + (size_t)(w * 48 + nt * 16 + l15) * 1024 + k0 + kc * 32 + g * 8);
        __syncthreads();
        #pragma unroll
        for (int kc = 0; kc < 2; kc++) {
            bf16x8 af[4];
            #pragma unroll
            for (int rt = 0; rt < 4; rt++)
                af[rt] = *(const bf16x8*)&xs[cur][rt * 16 + l15][kc * 32 + g * 8];
            #pragma unroll
            for (int rt = 0; rt < 4; rt++)
                #pragma unroll
                for (int nt = 0; nt < 3; nt++)
                    acc[rt][nt] = __builtin_amdgcn_mfma_f32_16x16x32_bf16(
                        af[rt], bfrag[nt][kc], acc[rt][nt], 0, 0, 0);
        }
        if (ks < 15) {   // write next tile into the other buffer
            #pragma unroll
            for (int i = 0; i < 4; i++) {
                s16x4 s = { f2bf(xr[i].x), f2bf(xr[i].y), f2bf(xr[i].z), f2bf(xr[i].w) };
                *(s16x4*)&xs[cur ^ 1][xrow][xquad * 16 + i * 4] = s;
            }
        }
        cur ^= 1;
    }

    const int bi  = r0 >> 11;
    const int sl0 = r0 & 2047;
    #pragma unroll
    for (int rt = 0; rt < 4; rt++)
        #pragma unroll
        for (int nt = 0; nt < 3; nt++) {
            const int c = w * 48 + nt * 16 + l15;
            #pragma unroll
            for (int r = 0; r < 4; r++) {
                const int row = r0 + rt * 16 + g * 4 + r;
                const short v = f2bf(acc[rt][nt][r]);
                if (c < 64)        qb[(size_t)row * 64 + c] = v;
                else if (c < 128)  kb[(size_t)row * 64 + (c - 64)] = v;
                else               vsl[rt * 16 + g * 4 + r][c - 128] = v;
            }
        }
    __syncthreads();
    {   // vt[b][h][seq] cooperative write: thread owns (h, 16-seq segment)
        const int h = tid >> 2, seg = tid & 3;
        short tmp[16];
        #pragma unroll
        for (int j = 0; j < 16; j++) tmp[j] = vsl[seg * 16 + j][h];
        short* dst = vtb + ((size_t)bi * 64 + h) * TT + sl0 + seg * 16;
        #pragma unroll
        for (int j2 = 0; j2 < 2; j2++) {
            bf16x8 o;
            #pragma unroll
            for (int jj = 0; jj < 8; jj++) o[jj] = tmp[j2 * 8 + jj];
            *(bf16x8*)(dst + j2 * 8) = o;
        }
    }
}

// ---------------------------------------------------------------------------
// Flash attention v5 (measured-best): swapped QK^T + in-register softmax,
// split-kv over 8 waves with LDS merge, software-pipelined K/V loads.
// ---------------------------------------------------------------------------
__global__ __launch_bounds__(512, 2)
void attn_kernel(
    const short* __restrict__ qb, const short* __restrict__ kb,
    const short* __restrict__ vtb, float* __restrict__ out)
{
    __shared__ __align__(16) char smem[AW * 4608];
    __shared__ float ml[AW][64];   // [w][0..31]=m, [w][32..63]=l

    const int tid  = threadIdx.x;
    const int w    = tid >> 6, lane = tid & 63;
    const int l15  = lane & 15, g = lane >> 4;
    const int b    = blockIdx.x & 7;
    const int qt   = 63 - (blockIdx.x >> 3);
    const int r0   = qt * 32;
    const int nkv  = (r0 >> 6) + 1;

    short* ps = (short*)(smem + w * 4608);   // [32][72]

    const short* q  = qb  + (size_t)b * TT * 64;
    const short* k  = kb  + (size_t)b * TT * 64;
    const short* vt = vtb + (size_t)b * 64 * TT;

    bf16x8 qf[2][2];
    #pragma unroll
    for (int rt = 0; rt < 2; rt++)
        #pragma unroll
        for (int kc = 0; kc < 2; kc++)
            qf[rt][kc] = *(const bf16x8*)(q + (size_t)(r0 + rt * 16 + l15) * 64 + kc * 32 + g * 8);

    f32x4 o[2][4];
    float m_[2] = { -INFINITY, -INFINITY };
    float l_[2] = { 0.f, 0.f };
    #pragma unroll
    for (int rt = 0; rt < 2; rt++)
        #pragma unroll
        for (int ht = 0; ht < 4; ht++) o[rt][ht] = (f32x4){0.f, 0.f, 0.f, 0.f};

    bf16x8 kf[4][2];
    if (w < nkv) {
        #pragma unroll
        for (int nt = 0; nt < 4; nt++)
            #pragma unroll
            for (int kc = 0; kc < 2; kc++)
                kf[nt][kc] = *(const bf16x8*)(
                    k + (size_t)(w * 64 + nt * 16 + l15) * 64 + kc * 32 + g * 8);
    }

    for (int t = w; t < nkv; t += AW) {
        const int s0 = t * 64;
        const bool diag = (t == nkv - 1);
        const bool more = (t + AW < nkv);

        f32x4 s[2][4];
        #pragma unroll
        for (int rt = 0; rt < 2; rt++)
            #pragma unroll
            for (int nt = 0; nt < 4; nt++) s[rt][nt] = (f32x4){0.f, 0.f, 0.f, 0.f};
        #pragma unroll
        for (int kc = 0; kc < 2; kc++)
            #pragma unroll
            for (int rt = 0; rt < 2; rt++)
                #pragma unroll
                for (int nt = 0; nt < 4; nt++)
                    s[rt][nt] = __builtin_amdgcn_mfma_f32_16x16x32_bf16(
                        kf[nt][kc], qf[rt][kc], s[rt][nt], 0, 0, 0);

        bf16x8 vf[4][2];
        #pragma unroll
        for (int ht = 0; ht < 4; ht++)
            #pragma unroll
            for (int kc = 0; kc < 2; kc++)
                vf[ht][kc] = *(const bf16x8*)(
                    vt + (size_t)(ht * 16 + l15) * TT + s0 + kc * 32 + g * 8);
        bf16x8 kfn[4][2];
        if (more) {
            #pragma unroll
            for (int nt = 0; nt < 4; nt++)
                #pragma unroll
                for (int kc = 0; kc < 2; kc++)
                    kfn[nt][kc] = *(const bf16x8*)(
                        k + (size_t)(s0 + AW * 64 + nt * 16 + l15) * 64 + kc * 32 + g * 8);
        }

        if (diag) {
            #pragma unroll
            for (int rt = 0; rt < 2; rt++) {
                const int qg = r0 + rt * 16 + l15;
                #pragma unroll
                for (int nt = 0; nt < 4; nt++)
                    #pragma unroll
                    for (int r = 0; r < 4; r++)
                        if (s0 + nt * 16 + g * 4 + r > qg) s[rt][nt][r] = -INFINITY;
            }
        }

        #pragma unroll
        for (int rt = 0; rt < 2; rt++) {
            float a0 = fmaxf(fmaxf(s[rt][0][0], s[rt][0][1]), fmaxf(s[rt][0][2], s[rt][0][3]));
            float a1 = fmaxf(fmaxf(s[rt][1][0], s[rt][1][1]), fmaxf(s[rt][1][2], s[rt][1][3]));
            float a2 = fmaxf(fmaxf(s[rt][2][0], s[rt][2][1]), fmaxf(s[rt][2][2], s[rt][2][3]));
            float a3 = fmaxf(fmaxf(s[rt][3][0], s[rt][3][1]), fmaxf(s[rt][3][2], s[rt][3][3]));
            float tm = fmaxf(fmaxf(a0, a1), fmaxf(a2, a3));
            tm = fmaxf(tm, __shfl_xor(tm, 16));
            tm = fmaxf(tm, __shfl_xor(tm, 32));

            const float mn = fmaxf(m_[rt], tm);
            const float al = __builtin_amdgcn_exp2f(m_[rt] - mn);
            m_[rt] = mn;

            #pragma unroll
            for (int nt = 0; nt < 4; nt++)
                #pragma unroll
                for (int r = 0; r < 4; r++)
                    s[rt][nt][r] = __builtin_amdgcn_exp2f(s[rt][nt][r] - mn);

            float b0 = (s[rt][0][0] + s[rt][0][1]) + (s[rt][0][2] + s[rt][0][3]);
            float b1 = (s[rt][1][0] + s[rt][1][1]) + (s[rt][1][2] + s[rt][1][3]);
            float b2 = (s[rt][2][0] + s[rt][2][1]) + (s[rt][2][2] + s[rt][2][3]);
            float b3 = (s[rt][3][0] + s[rt][3][1]) + (s[rt][3][2] + s[rt][3][3]);
            float ts = (b0 + b1) + (b2 + b3);
            ts += __shfl_xor(ts, 16);
            ts += __shfl_xor(ts, 32);
            l_[rt] = l_[rt] * al + ts;

            float ab[4];
            #pragma unroll
            for (int r = 0; r < 4; r++) ab[r] = __shfl(al, g * 4 + r);
            #pragma unroll
            for (int ht = 0; ht < 4; ht++)
                #pragma unroll
                for (int r = 0; r < 4; r++)
                    o[rt][ht][r] *= ab[r];

            #pragma unroll
            for (int nt = 0; nt < 4; nt++) {
                s16x4 pk = { f2bf(s[rt][nt][0]), f2bf(s[rt][nt][1]),
                             f2bf(s[rt][nt][2]), f2bf(s[rt][nt][3]) };
                *(s16x4*)&ps[(rt * 16 + l15) * 72 + nt * 16 + g * 4] = pk;
            }
        }

        bf16x8 pf[2][2];
        #pragma unroll
        for (int rt = 0; rt < 2; rt++)
            #pragma unroll
            for (int kc = 0; kc < 2; kc++)
                pf[rt][kc] = *(const bf16x8*)&ps[(rt * 16 + l15) * 72 + kc * 32 + g * 8];
        #pragma unroll
        for (int kc = 0; kc < 2; kc++)
            #pragma unroll
            for (int rt = 0; rt < 2; rt++)
                #pragma unroll
                for (int ht = 0; ht < 4; ht++)
                    o[rt][ht] = __builtin_amdgcn_mfma_f32_16x16x32_bf16(
                        pf[rt][kc], vf[ht][kc], o[rt][ht], 0, 0, 0);

        if (more) {
            #pragma unroll
            for (int nt = 0; nt < 4; nt++)
                #pragma unroll
                for (int kc = 0; kc < 2; kc++)
                    kf[nt][kc] = kfn[nt][kc];
        }
    }

    if (g == 0) {
        #pragma unroll
        for (int rt = 0; rt < 2; rt++) {
            ml[w][rt * 16 + l15]      = m_[rt];
            ml[w][32 + rt * 16 + l15] = l_[rt];
        }
    }
    short* pO = ps;   // [32][68] bf16 (ps is dead now)
    #pragma unroll
    for (int rt = 0; rt < 2; rt++)
        #pragma unroll
        for (int ht = 0; ht < 4; ht++)
            #pragma unroll
            for (int r = 0; r < 4; r++)
                pO[(rt * 16 + g * 4 + r) * 68 + ht * 16 + l15] = f2bf(o[rt][ht][r]);
    __syncthreads();

    {
        const int row = tid >> 4, seg = tid & 15;
        float gm = -INFINITY;
        #pragma unroll
        for (int w2 = 0; w2 < AW; w2++) gm = fmaxf(gm, ml[w2][row]);
        float accL = 0.f;
        float accO[4] = {0.f, 0.f, 0.f, 0.f};
        #pragma unroll
        for (int w2 = 0; w2 < AW; w2++) {
            const float sc = __builtin_amdgcn_exp2f(ml[w2][row] - gm);
            accL = fmaf(sc, ml[w2][32 + row], accL);
            const s16x4 ov = *(const s16x4*)((const short*)(smem + w2 * 4608) + row * 68 + seg * 4);
            #pragma unroll
            for (int j = 0; j < 4; j++)
                accO[j] = fmaf(sc, bf2f(ov[j]), accO[j]);
        }
        const float inv = 1.f / accL;
        float4 res = make_float4(accO[0] * inv, accO[1] * inv, accO[2] * inv, accO[3] * inv);
        *(float4*)(out + ((size_t)b * TT + r0 + row) * 64 + seg * 4) = res;
    }
}

extern "C" void kernel_launch(void* const* d_in, const int* in_sizes, int n_in,
                              void* d_out, int out_size, void* d_ws, size_t ws_size,
                              hipStream_t stream) {
    const float* x  = (const float*)d_in[0];
    const float* Wk = (const float*)d_in[1];
    const float* Wq = (const float*)d_in[2];
    const float* Wv = (const float*)d_in[3];
    float* outp = (float*)d_out;

    short* wt  = (short*)d_ws;                     // [192][1024] bf16
    short* qb  = wt + (size_t)192 * 1024;          // [16384][64] bf16 (pre-scaled)
    short* kb  = qb + (size_t)MROWS * 64;          // [16384][64] bf16
    short* vtb = kb + (size_t)MROWS * 64;          // [8][64][2048] bf16 (V^T)

    wtrans_kernel<<<48, 256, 0, stream>>>(Wk, Wq, Wv, wt);
    proj_kernel<<<MROWS / 64, 256, 0, stream>>>(x, wt, qb, kb, vtb);
    attn_kernel<<<BATCH * 64, 512, 0, stream>>>(qb, kb, vtb, outp);
}

// Round 15
// 47.170 us; speedup vs baseline: 1.4728x; 1.1252x over previous
//
#include <hip/hip_runtime.h>
#include <hip/hip_bf16.h>

#define TT 2048
#define BATCH 8
#define MROWS (BATCH*TT)   // 16384
#define AW 8               // waves per attn block

typedef __attribute__((ext_vector_type(8))) short bf16x8;   // MFMA A/B frag (4 VGPR)
typedef __attribute__((ext_vector_type(4))) short s16x4;
typedef __attribute__((ext_vector_type(4))) float f32x4;    // MFMA C/D frag

__device__ __forceinline__ short f2bf(float f) {
    union { __hip_bfloat16 h; short s; } u;
    u.h = __float2bfloat16(f);
    return u.s;
}
__device__ __forceinline__ float bf2f(short s) {
    union { unsigned u; float f; } u;
    u.u = ((unsigned)(unsigned short)s) << 16;
    return u.f;
}

typedef __attribute__((address_space(3))) unsigned int       lds_u32_t;
typedef const __attribute__((address_space(1))) unsigned int g_u32_t;
__device__ __forceinline__ void gl_lds16(const void* g, void* l) {
    __builtin_amdgcn_global_load_lds((g_u32_t*)g, (lds_u32_t*)l, 16, 0, 0);
}

// ---------------------------------------------------------------------------
// W transpose: Wq|Wk|Wv [1024][64] f32 -> wt [192][1024] bf16 (row n = col of W)
// Wq gets scale = (1/32)*log2(e) folded in (softmax scale + exp->exp2).
// ---------------------------------------------------------------------------
__global__ __launch_bounds__(256) void wtrans_kernel(
    const float* __restrict__ Wk, const float* __restrict__ Wq,
    const float* __restrict__ Wv, short* __restrict__ wt)
{
    __shared__ float tile[64][68];
    const int mat = blockIdx.x >> 4;           // 0=q,1=k,2=v
    const int k0  = (blockIdx.x & 15) * 64;
    const float* W = (mat == 0) ? Wq : (mat == 1) ? Wk : Wv;
    const float scl = (mat == 0) ? 0.04508422002778011f : 1.0f;  // (1/32)*log2(e)
    const int t = threadIdx.x;
    const int row = t >> 2, quad = t & 3;
    #pragma unroll
    for (int i = 0; i < 4; i++) {
        float4 v = *(const float4*)(W + (size_t)(k0 + row) * 64 + quad * 16 + i * 4);
        *(float4*)&tile[row][quad * 16 + i * 4] = v;
    }
    __syncthreads();
    short tmp[16];
    #pragma unroll
    for (int j = 0; j < 16; j++) tmp[j] = f2bf(tile[quad * 16 + j][row] * scl);
    short* dst = wt + (size_t)(mat * 64 + row) * 1024 + k0 + quad * 16;
    #pragma unroll
    for (int j2 = 0; j2 < 2; j2++) {
        bf16x8 o;
        #pragma unroll
        for (int jj = 0; jj < 8; jj++) o[jj] = tmp[j2 * 8 + jj];
        *(bf16x8*)(dst + j2 * 8) = o;
    }
}

// ---------------------------------------------------------------------------
// Projection v5 (measured-best, R8): BM=32, BN=192, BK=64, 256 thr, 512
// blocks (2/CU interleaved). Both operands staged via async global_load_lds
// (16B); XOR bank-swizzle via pre-swizzled per-lane GLOBAL source + swizzled
// LDS read (rule 21). 2-phase loop: stage(t+1) -> compute(t) -> barrier.
// ---------------------------------------------------------------------------
__global__ __launch_bounds__(256, 2) void proj_kernel(
    const float* __restrict__ x, const short* __restrict__ wt,
    short* __restrict__ qb, short* __restrict__ kb, short* __restrict__ vtb)
{
    // [0,16384): As [2][32][64] f32 (8192 B/buf)
    // [16384,65536): Bs [2][192][64] bf16 (24576 B/buf)
    __shared__ __align__(16) char lds[65536];

    const int tid  = threadIdx.x;
    const int lane = tid & 63, w = tid >> 6;
    const int l15  = lane & 15, g = lane >> 4;
    const int x7   = l15 & 7;
    const int wr   = w & 1;              // row group: rows wr*16..+15
    const int wc   = w >> 1;             // col group: cols wc*96..+95
    const int r0   = blockIdx.x * 32;

    // ---- staging addresses (per-lane global src pre-swizzled; LDS linear)
    const float* ag[2]; unsigned aOff[2];
    #pragma unroll
    for (int j = 0; j < 2; j++) {
        const int jp   = w * 2 + j;                 // issue 0..7, 4 rows each
        const int row  = jp * 4 + (lane >> 4);
        const int slot = (lane & 15) ^ (row & 7);
        ag[j]   = x + (size_t)(r0 + row) * 1024 + slot * 4;
        aOff[j] = jp * 1024;
    }
    const short* bg[6]; unsigned bOff[6];
    #pragma unroll
    for (int j = 0; j < 6; j++) {
        const int jp   = w * 6 + j;                 // issue 0..23, 8 rows each
        const int row  = jp * 8 + (lane >> 3);
        const int slot = (lane & 7) ^ (row & 7);
        bg[j]   = wt + (size_t)row * 1024 + slot * 8;
        bOff[j] = 16384 + jp * 1024;
    }

    f32x4 acc[6];
    #pragma unroll
    for (int nt = 0; nt < 6; nt++) acc[nt] = (f32x4){0.f, 0.f, 0.f, 0.f};

    // prologue: stage k-tile 0 into buffer 0
    #pragma unroll
    for (int j = 0; j < 2; j++) gl_lds16(ag[j], lds + aOff[j]);
    #pragma unroll
    for (int j = 0; j < 6; j++) gl_lds16(bg[j], lds + bOff[j]);
    __syncthreads();

    #pragma unroll
    for (int ks = 0; ks < 16; ks++) {
        const int cur = ks & 1;

        // issue async staging for next tile (lands by end-of-step barrier)
        if (ks < 15) {
            const int nb = cur ^ 1;
            #pragma unroll
            for (int j = 0; j < 2; j++)
                gl_lds16(ag[j] + (ks + 1) * 64, lds + nb * 8192 + aOff[j]);
            #pragma unroll
            for (int j = 0; j < 6; j++)
                gl_lds16(bg[j] + (ks + 1) * 64, lds + nb * 24576 + bOff[j]);
        }

        const float* Ab = (const float*)(lds + cur * 8192);
        const short* Bb = (const short*)(lds + 16384 + cur * 24576);

        // A frags: fp32 from LDS (swizzled slots), convert to bf16
        bf16x8 af[2];
        #pragma unroll
        for (int kc = 0; kc < 2; kc++) {
            const int arow = wr * 16 + l15;
            f32x4 lo = *(const f32x4*)(Ab + arow * 64 + ((kc * 8 + 2 * g)     ^ x7) * 4);
            f32x4 hi = *(const f32x4*)(Ab + arow * 64 + ((kc * 8 + 2 * g + 1) ^ x7) * 4);
            af[kc] = (bf16x8){ f2bf(lo[0]), f2bf(lo[1]), f2bf(lo[2]), f2bf(lo[3]),
                               f2bf(hi[0]), f2bf(hi[1]), f2bf(hi[2]), f2bf(hi[3]) };
        }
        // B frags (bf16, swizzled slots)
        bf16x8 bfr[6][2];
        #pragma unroll
        for (int nt = 0; nt < 6; nt++)
            #pragma unroll
            for (int kc = 0; kc < 2; kc++)
                bfr[nt][kc] = *(const bf16x8*)(
                    Bb + (wc * 96 + nt * 16 + l15) * 64 + ((kc * 4 + g) ^ x7) * 8);

        #pragma unroll
        for (int kc = 0; kc < 2; kc++)
            #pragma unroll
            for (int nt = 0; nt < 6; nt++)
                acc[nt] = __builtin_amdgcn_mfma_f32_16x16x32_bf16(
                    af[kc], bfr[nt][kc], acc[nt], 0, 0, 0);

        __syncthreads();
    }

    // ---- epilogue: q,k direct; v via LDS transpose (overlay on As region)
    const int bi  = r0 >> 11;
    const int sl0 = r0 & 2047;
    short* vsl = (short*)lds;            // [32][66]
    #pragma unroll
    for (int nt = 0; nt < 6; nt++) {
        const int c = wc * 96 + nt * 16 + l15;
        #pragma unroll
        for (int r = 0; r < 4; r++) {
            const int row = r0 + wr * 16 + g * 4 + r;
            const short v = f2bf(acc[nt][r]);
            if (c < 64)        qb[(size_t)row * 64 + c] = v;
            else if (c < 128)  kb[(size_t)row * 64 + (c - 64)] = v;
            else               vsl[(wr * 16 + g * 4 + r) * 66 + (c - 128)] = v;
        }
    }
    __syncthreads();
    {   // vt[b][col][seq]: thread owns (col, 8-seq segment)
        const int col = tid >> 2, seg = tid & 3;
        short tmp[8];
        #pragma unroll
        for (int j = 0; j < 8; j++) tmp[j] = vsl[(seg * 8 + j) * 66 + col];
        bf16x8 o;
        #pragma unroll
        for (int jj = 0; jj < 8; jj++) o[jj] = tmp[jj];
        *(bf16x8*)(vtb + ((size_t)bi * 64 + col) * TT + sl0 + seg * 8) = o;
    }
}

// ---------------------------------------------------------------------------
// Flash attention v5 (measured-best): swapped QK^T + in-register softmax,
// split-kv over 8 waves with LDS merge, software-pipelined K/V loads.
// ---------------------------------------------------------------------------
__global__ __launch_bounds__(512, 2)
void attn_kernel(
    const short* __restrict__ qb, const short* __restrict__ kb,
    const short* __restrict__ vtb, float* __restrict__ out)
{
    __shared__ __align__(16) char smem[AW * 4608];
    __shared__ float ml[AW][64];   // [w][0..31]=m, [w][32..63]=l

    const int tid  = threadIdx.x;
    const int w    = tid >> 6, lane = tid & 63;
    const int l15  = lane & 15, g = lane >> 4;
    const int b    = blockIdx.x & 7;
    const int qt   = 63 - (blockIdx.x >> 3);
    const int r0   = qt * 32;
    const int nkv  = (r0 >> 6) + 1;

    short* ps = (short*)(smem + w * 4608);   // [32][72]

    const short* q  = qb  + (size_t)b * TT * 64;
    const short* k  = kb  + (size_t)b * TT * 64;
    const short* vt = vtb + (size_t)b * 64 * TT;

    bf16x8 qf[2][2];
    #pragma unroll
    for (int rt = 0; rt < 2; rt++)
        #pragma unroll
        for (int kc = 0; kc < 2; kc++)
            qf[rt][kc] = *(const bf16x8*)(q + (size_t)(r0 + rt * 16 + l15) * 64 + kc * 32 + g * 8);

    f32x4 o[2][4];
    float m_[2] = { -INFINITY, -INFINITY };
    float l_[2] = { 0.f, 0.f };
    #pragma unroll
    for (int rt = 0; rt < 2; rt++)
        #pragma unroll
        for (int ht = 0; ht < 4; ht++) o[rt][ht] = (f32x4){0.f, 0.f, 0.f, 0.f};

    bf16x8 kf[4][2];
    if (w < nkv) {
        #pragma unroll
        for (int nt = 0; nt < 4; nt++)
            #pragma unroll
            for (int kc = 0; kc < 2; kc++)
                kf[nt][kc] = *(const bf16x8*)(
                    k + (size_t)(w * 64 + nt * 16 + l15) * 64 + kc * 32 + g * 8);
    }

    for (int t = w; t < nkv; t += AW) {
        const int s0 = t * 64;
        const bool diag = (t == nkv - 1);
        const bool more = (t + AW < nkv);

        f32x4 s[2][4];
        #pragma unroll
        for (int rt = 0; rt < 2; rt++)
            #pragma unroll
            for (int nt = 0; nt < 4; nt++) s[rt][nt] = (f32x4){0.f, 0.f, 0.f, 0.f};
        #pragma unroll
        for (int kc = 0; kc < 2; kc++)
            #pragma unroll
            for (int rt = 0; rt < 2; rt++)
                #pragma unroll
                for (int nt = 0; nt < 4; nt++)
                    s[rt][nt] = __builtin_amdgcn_mfma_f32_16x16x32_bf16(
                        kf[nt][kc], qf[rt][kc], s[rt][nt], 0, 0, 0);

        bf16x8 vf[4][2];
        #pragma unroll
        for (int ht = 0; ht < 4; ht++)
            #pragma unroll
            for (int kc = 0; kc < 2; kc++)
                vf[ht][kc] = *(const bf16x8*)(
                    vt + (size_t)(ht * 16 + l15) * TT + s0 + kc * 32 + g * 8);
        bf16x8 kfn[4][2];
        if (more) {
            #pragma unroll
            for (int nt = 0; nt < 4; nt++)
                #pragma unroll
                for (int kc = 0; kc < 2; kc++)
                    kfn[nt][kc] = *(const bf16x8*)(
                        k + (size_t)(s0 + AW * 64 + nt * 16 + l15) * 64 + kc * 32 + g * 8);
        }

        if (diag) {
            #pragma unroll
            for (int rt = 0; rt < 2; rt++) {
                const int qg = r0 + rt * 16 + l15;
                #pragma unroll
                for (int nt = 0; nt < 4; nt++)
                    #pragma unroll
                    for (int r = 0; r < 4; r++)
                        if (s0 + nt * 16 + g * 4 + r > qg) s[rt][nt][r] = -INFINITY;
            }
        }

        #pragma unroll
        for (int rt = 0; rt < 2; rt++) {
            float a0 = fmaxf(fmaxf(s[rt][0][0], s[rt][0][1]), fmaxf(s[rt][0][2], s[rt][0][3]));
            float a1 = fmaxf(fmaxf(s[rt][1][0], s[rt][1][1]), fmaxf(s[rt][1][2], s[rt][1][3]));
            float a2 = fmaxf(fmaxf(s[rt][2][0], s[rt][2][1]), fmaxf(s[rt][2][2], s[rt][2][3]));
            float a3 = fmaxf(fmaxf(s[rt][3][0], s[rt][3][1]), fmaxf(s[rt][3][2], s[rt][3][3]));
            float tm = fmaxf(fmaxf(a0, a1), fmaxf(a2, a3));
            tm = fmaxf(tm, __shfl_xor(tm, 16));
            tm = fmaxf(tm, __shfl_xor(tm, 32));

            const float mn = fmaxf(m_[rt], tm);
            const float al = __builtin_amdgcn_exp2f(m_[rt] - mn);
            m_[rt] = mn;

            #pragma unroll
            for (int nt = 0; nt < 4; nt++)
                #pragma unroll
                for (int r = 0; r < 4; r++)
                    s[rt][nt][r] = __builtin_amdgcn_exp2f(s[rt][nt][r] - mn);

            float b0 = (s[rt][0][0] + s[rt][0][1]) + (s[rt][0][2] + s[rt][0][3]);
            float b1 = (s[rt][1][0] + s[rt][1][1]) + (s[rt][1][2] + s[rt][1][3]);
            float b2 = (s[rt][2][0] + s[rt][2][1]) + (s[rt][2][2] + s[rt][2][3]);
            float b3 = (s[rt][3][0] + s[rt][3][1]) + (s[rt][3][2] + s[rt][3][3]);
            float ts = (b0 + b1) + (b2 + b3);
            ts += __shfl_xor(ts, 16);
            ts += __shfl_xor(ts, 32);
            l_[rt] = l_[rt] * al + ts;

            float ab[4];
            #pragma unroll
            for (int r = 0; r < 4; r++) ab[r] = __shfl(al, g * 4 + r);
            #pragma unroll
            for (int ht = 0; ht < 4; ht++)
                #pragma unroll
                for (int r = 0; r < 4; r++)
                    o[rt][ht][r] *= ab[r];

            #pragma unroll
            for (int nt = 0; nt < 4; nt++) {
                s16x4 pk = { f2bf(s[rt][nt][0]), f2bf(s[rt][nt][1]),
                             f2bf(s[rt][nt][2]), f2bf(s[rt][nt][3]) };
                *(s16x4*)&ps[(rt * 16 + l15) * 72 + nt * 16 + g * 4] = pk;
            }
        }

        bf16x8 pf[2][2];
        #pragma unroll
        for (int rt = 0; rt < 2; rt++)
            #pragma unroll
            for (int kc = 0; kc < 2; kc++)
                pf[rt][kc] = *(const bf16x8*)&ps[(rt * 16 + l15) * 72 + kc * 32 + g * 8];
        #pragma unroll
        for (int kc = 0; kc < 2; kc++)
            #pragma unroll
            for (int rt = 0; rt < 2; rt++)
                #pragma unroll
                for (int ht = 0; ht < 4; ht++)
                    o[rt][ht] = __builtin_amdgcn_mfma_f32_16x16x32_bf16(
                        pf[rt][kc], vf[ht][kc], o[rt][ht], 0, 0, 0);

        if (more) {
            #pragma unroll
            for (int nt = 0; nt < 4; nt++)
                #pragma unroll
                for (int kc = 0; kc < 2; kc++)
                    kf[nt][kc] = kfn[nt][kc];
        }
    }

    if (g == 0) {
        #pragma unroll
        for (int rt = 0; rt < 2; rt++) {
            ml[w][rt * 16 + l15]      = m_[rt];
            ml[w][32 + rt * 16 + l15] = l_[rt];
        }
    }
    short* pO = ps;   // [32][68] bf16 (ps is dead now)
    #pragma unroll
    for (int rt = 0; rt < 2; rt++)
        #pragma unroll
        for (int ht = 0; ht < 4; ht++)
            #pragma unroll
            for (int r = 0; r < 4; r++)
                pO[(rt * 16 + g * 4 + r) * 68 + ht * 16 + l15] = f2bf(o[rt][ht][r]);
    __syncthreads();

    {
        const int row = tid >> 4, seg = tid & 15;
        float gm = -INFINITY;
        #pragma unroll
        for (int w2 = 0; w2 < AW; w2++) gm = fmaxf(gm, ml[w2][row]);
        float accL = 0.f;
        float accO[4] = {0.f, 0.f, 0.f, 0.f};
        #pragma unroll
        for (int w2 = 0; w2 < AW; w2++) {
            const float sc = __builtin_amdgcn_exp2f(ml[w2][row] - gm);
            accL = fmaf(sc, ml[w2][32 + row], accL);
            const s16x4 ov = *(const s16x4*)((const short*)(smem + w2 * 4608) + row * 68 + seg * 4);
            #pragma unroll
            for (int j = 0; j < 4; j++)
                accO[j] = fmaf(sc, bf2f(ov[j]), accO[j]);
        }
        const float inv = 1.f / accL;
        float4 res = make_float4(accO[0] * inv, accO[1] * inv, accO[2] * inv, accO[3] * inv);
        *(float4*)(out + ((size_t)b * TT + r0 + row) * 64 + seg * 4) = res;
    }
}

extern "C" void kernel_launch(void* const* d_in, const int* in_sizes, int n_in,
                              void* d_out, int out_size, void* d_ws, size_t ws_size,
                              hipStream_t stream) {
    const float* x  = (const float*)d_in[0];
    const float* Wk = (const float*)d_in[1];
    const float* Wq = (const float*)d_in[2];
    const float* Wv = (const float*)d_in[3];
    float* outp = (float*)d_out;

    short* wt  = (short*)d_ws;                     // [192][1024] bf16
    short* qb  = wt + (size_t)192 * 1024;          // [16384][64] bf16 (pre-scaled)
    short* kb  = qb + (size_t)MROWS * 64;          // [16384][64] bf16
    short* vtb = kb + (size_t)MROWS * 64;          // [8][64][2048] bf16 (V^T)

    wtrans_kernel<<<48, 256, 0, stream>>>(Wk, Wq, Wv, wt);
    proj_kernel<<<MROWS / 32, 256, 0, stream>>>(x, wt, qb, kb, vtb);
    attn_kernel<<<BATCH * 64, 512, 0, stream>>>(qb, kb, vtb, outp);
}